// Round 16
// baseline (1638.810 us; speedup 1.0000x reference)
//
#include <hip/hip_runtime.h>
#include <stdint.h>
#include <stddef.h>

typedef __attribute__((ext_vector_type(8))) short short8;
typedef __attribute__((ext_vector_type(4))) float f32x4;
typedef unsigned int u32;

__device__ inline unsigned short f2bf(float f) {
  union { float f; uint32_t u; } v; v.f = f;
  uint32_t u = v.u;
  u += 0x7FFFu + ((u >> 16) & 1u);
  return (unsigned short)(u >> 16);
}
__device__ inline float bf2f(unsigned short h) {
  union { uint32_t u; float f; } v; v.u = ((uint32_t)h) << 16; return v.f;
}
__device__ inline float bflo(u32 v) {
  union { u32 u; float f; } x; x.u = v << 16; return x.f;
}
__device__ inline float bfhi(u32 v) {
  union { u32 u; float f; } x; x.u = v & 0xffff0000u; return x.f;
}
__device__ inline short8 pack8(float4 a, float4 b) {
  short8 r;
  r[0] = (short)f2bf(a.x); r[1] = (short)f2bf(a.y);
  r[2] = (short)f2bf(a.z); r[3] = (short)f2bf(a.w);
  r[4] = (short)f2bf(b.x); r[5] = (short)f2bf(b.y);
  r[6] = (short)f2bf(b.z); r[7] = (short)f2bf(b.w);
  return r;
}
__device__ inline float tanh_fast(float x) {
  float xc = fminf(fmaxf(x, -9.f), 9.f);
  float e = __expf(2.f * xc);
  return (e - 1.f) * __builtin_amdgcn_rcpf(e + 1.f);
}
__device__ inline float sigm_fast(float x) {
  float xc = fminf(fmaxf(x, -30.f), 30.f);
  return __builtin_amdgcn_rcpf(1.f + __expf(-xc));
}
// async global->LDS, 16 bytes per lane (wave-uniform LDS base + lane*16)
__device__ inline void gl_lds16(const unsigned short* g, unsigned short* l) {
  __builtin_amdgcn_global_load_lds(
      (const __attribute__((address_space(1))) u32*)g,
      (__attribute__((address_space(3))) u32*)l, 16, 0, 0);
}

// Gather + bf16-convert embeddings. Blocks 3584..3623 zero d_out rows 0..31
// and h state buffers; blocks 3624..8743 do the weight f32->bf16 conversions.
__global__ __launch_bounds__(128) void prep_gather(
    const int* __restrict__ src, const int* __restrict__ trg,
    const float* __restrict__ emb,
    unsigned short* __restrict__ xbf, unsigned short* __restrict__ ebf,
    unsigned short* __restrict__ Zbf,
    float* __restrict__ outZero,
    unsigned short* __restrict__ hbf,
    float* __restrict__ hf32,
    const float* __restrict__ encfW, const float* __restrict__ encbW,
    const float* __restrict__ attnW, const float* __restrict__ decWhh,
    unsigned short* __restrict__ whFbf, unsigned short* __restrict__ whBbf,
    unsigned short* __restrict__ Wcat) {
  int r = blockIdx.x, tid = threadIdx.x;
  if (r >= 3624) {
    if (tid >= 64) return;
    int q = r - 3624;
    int c = tid * 8;
    const float* s;
    unsigned short* d;
    if (q < 1536) { s = encfW + (size_t)q * 512 + c; d = whFbf + (size_t)q * 512 + c; }
    else if (q < 3072) { int u = q - 1536; s = encbW + (size_t)u * 512 + c; d = whBbf + (size_t)u * 512 + c; }
    else if (q < 3584) { int u = q - 3072; s = attnW + (size_t)u * 1536 + c; d = Wcat + (size_t)u * 512 + c; }
    else { int u = q - 3584; s = decWhh + (size_t)u * 512 + c; d = Wcat + (size_t)(u + 512) * 512 + c; }
    *(short8*)d = pack8(*(const float4*)s, *(const float4*)(s + 4));
    return;
  }
  if (r >= 3584) {
    int z = r - 3584;
    if (z < 32) {
      float4* dst = (float4*)(outZero + (size_t)z * 32000);
      for (int i = tid; i < 8000; i += 128) dst[i] = (float4){0.f, 0.f, 0.f, 0.f};
    } else if (z < 36) {
      float4* dst = (float4*)(hbf + (size_t)(z - 32) * 32768);
      for (int i = tid; i < 4096; i += 128) dst[i] = (float4){0.f, 0.f, 0.f, 0.f};
    } else if (z < 40) {
      float4* dst = (float4*)(hf32 + (size_t)(z - 36) * 32768);
      for (int i = tid; i < 8192; i += 128) dst[i] = (float4){0.f, 0.f, 0.f, 0.f};
    }
    return;
  }
  if (r < 2048) {
    int b = r & 31, s = r >> 5;
    int tok = src[b * 64 + s];
    const float* e = emb + (size_t)tok * 512;
    float4 v = *(const float4*)(e + tid * 4);
    unsigned short* dst = xbf + (size_t)r * 512 + tid * 4;
    dst[0] = f2bf(v.x); dst[1] = f2bf(v.y); dst[2] = f2bf(v.z); dst[3] = f2bf(v.w);
  } else {
    int rr = r - 2048;
    int t = rr >> 5, b = rr & 31;
    unsigned short* dst = ebf + (size_t)rr * 512 + tid * 4;
    if (t < 47) {
      int tok = trg[t * 32 + b];
      const float* e = emb + (size_t)tok * 512;
      float4 v = *(const float4*)(e + tid * 4);
      unsigned short q0 = f2bf(v.x), q1 = f2bf(v.y), q2 = f2bf(v.z), q3 = f2bf(v.w);
      dst[0] = q0; dst[1] = q1; dst[2] = q2; dst[3] = q3;
      unsigned short* zd = Zbf + (size_t)rr * 2048 + 1536 + tid * 4;
      zd[0] = q0; zd[1] = q1; zd[2] = q2; zd[3] = q3;
    } else {
      dst[0] = 0; dst[1] = 0; dst[2] = 0; dst[3] = 0;
    }
  }
}

// Shared GEMM body: C[m,n] = sum_k A[m,k]*B[n,k] (+bias[n]).
template <bool ABF, bool BBF, bool WBF>
__device__ inline void gemm_body(
    const void* __restrict__ Av, int lda,
    const void* __restrict__ Bv, int ldb, int bco,
    const float* __restrict__ bias,
    void* __restrict__ Cv, int ldc,
    int K, int Mvalid, int row_off, int m0, int n0) {
  __shared__ __align__(16) unsigned short As[128 * 32];
  __shared__ __align__(16) unsigned short Bs[128 * 32];
  const int tid = threadIdx.x;
  const int w = tid >> 6, lane = tid & 63;
  const int wm = w >> 1, wn = w & 1;
  const int fr = lane & 15, fq = lane >> 4;
  f32x4 acc[4][4];
#pragma unroll
  for (int mi = 0; mi < 4; ++mi)
#pragma unroll
    for (int ni = 0; ni < 4; ++ni) acc[mi][ni] = (f32x4){0.f, 0.f, 0.f, 0.f};
  for (int k0 = 0; k0 < K; k0 += 32) {
#pragma unroll
    for (int p = 0; p < 2; ++p) {
      int idx = p * 256 + tid;
      int row = idx >> 2, seg = idx & 3;
      if (ABF) {
        const unsigned short* Ab = (const unsigned short*)Av;
        *(short8*)(As + row * 32 + seg * 8) =
            *(const short8*)(Ab + (size_t)(m0 + row) * lda + k0 + seg * 8);
      } else {
        const float* Af = (const float*)Av;
        const float* ap = Af + (size_t)(m0 + row) * lda + k0 + seg * 8;
        *(short8*)(As + row * 32 + seg * 8) = pack8(*(const float4*)ap, *(const float4*)(ap + 4));
      }
      if (BBF) {
        const unsigned short* Bb = (const unsigned short*)Bv;
        *(short8*)(Bs + row * 32 + seg * 8) =
            *(const short8*)(Bb + (size_t)(n0 + row) * ldb + bco + k0 + seg * 8);
      } else {
        const float* Bf = (const float*)Bv;
        const float* bp = Bf + (size_t)(n0 + row) * ldb + bco + k0 + seg * 8;
        *(short8*)(Bs + row * 32 + seg * 8) = pack8(*(const float4*)bp, *(const float4*)(bp + 4));
      }
    }
    __syncthreads();
    short8 af[4], bfr[4];
#pragma unroll
    for (int mi = 0; mi < 4; ++mi)
      af[mi] = *(const short8*)(As + (wm * 64 + mi * 16 + fr) * 32 + fq * 8);
#pragma unroll
    for (int ni = 0; ni < 4; ++ni)
      bfr[ni] = *(const short8*)(Bs + (wn * 64 + ni * 16 + fr) * 32 + fq * 8);
#pragma unroll
    for (int mi = 0; mi < 4; ++mi)
#pragma unroll
      for (int ni = 0; ni < 4; ++ni)
        acc[mi][ni] = __builtin_amdgcn_mfma_f32_16x16x32_bf16(af[mi], bfr[ni], acc[mi][ni], 0, 0, 0);
    __syncthreads();
  }
#pragma unroll
  for (int mi = 0; mi < 4; ++mi)
#pragma unroll
    for (int ni = 0; ni < 4; ++ni) {
      int col = n0 + wn * 64 + ni * 16 + fr;
      float bv = bias ? bias[col] : 0.f;
#pragma unroll
      for (int j = 0; j < 4; ++j) {
        int rowm = m0 + wm * 64 + mi * 16 + fq * 4 + j;
        if (rowm < Mvalid) {
          float val = acc[mi][ni][j] + bv;
          if (WBF)
            ((unsigned short*)Cv)[(size_t)(rowm + row_off) * ldc + col] = f2bf(val);
          else
            ((float*)Cv)[(size_t)(rowm + row_off) * ldc + col] = val;
        }
      }
    }
}

template <bool ABF, bool BBF, bool WBF>
__global__ __launch_bounds__(256) void gemm_kernel(
    const void* __restrict__ Av, int lda,
    const void* __restrict__ Bv, int ldb, int bco,
    const float* __restrict__ bias,
    void* __restrict__ Cv, int ldc,
    int K, int Mvalid, int row_off) {
  gemm_body<ABF, BBF, WBF>(Av, lda, Bv, ldb, bco, bias, Cv, ldc, K, Mvalid,
                           row_off, blockIdx.x * 128, blockIdx.y * 128);
}

// fc GEMM with tanh epilogue: s0 = tanh(hcat @ fc_W^T + fc_b).
__global__ __launch_bounds__(256) void gemm_fc(
    const float* __restrict__ hcat, const float* __restrict__ fcW,
    const float* __restrict__ fcb,
    float* __restrict__ sf32, unsigned short* __restrict__ sbf) {
  __shared__ __align__(16) unsigned short As[128 * 32];
  __shared__ __align__(16) unsigned short Bs[128 * 32];
  const int tid = threadIdx.x;
  const int n0 = blockIdx.x * 128;
  const int w = tid >> 6, lane = tid & 63;
  const int wm = w >> 1, wn = w & 1;
  const int fr = lane & 15, fq = lane >> 4;
  f32x4 acc[4][4];
#pragma unroll
  for (int mi = 0; mi < 4; ++mi)
#pragma unroll
    for (int ni = 0; ni < 4; ++ni) acc[mi][ni] = (f32x4){0.f, 0.f, 0.f, 0.f};
  for (int k0 = 0; k0 < 1024; k0 += 32) {
#pragma unroll
    for (int p = 0; p < 2; ++p) {
      int idx = p * 256 + tid;
      int row = idx >> 2, seg = idx & 3;
      if (row < 32) {
        const float* ap = hcat + (size_t)row * 1024 + k0 + seg * 8;
        *(short8*)(As + row * 32 + seg * 8) = pack8(*(const float4*)ap, *(const float4*)(ap + 4));
      }
      const float* bp = fcW + (size_t)(n0 + row) * 1024 + k0 + seg * 8;
      *(short8*)(Bs + row * 32 + seg * 8) = pack8(*(const float4*)bp, *(const float4*)(bp + 4));
    }
    __syncthreads();
    short8 af, bfr[4];
    af = *(const short8*)(As + ((wm == 0 ? fr : fr + 16)) * 32 + fq * 8);
#pragma unroll
    for (int ni = 0; ni < 4; ++ni)
      bfr[ni] = *(const short8*)(Bs + (wn * 64 + ni * 16 + fr) * 32 + fq * 8);
#pragma unroll
    for (int ni = 0; ni < 4; ++ni)
      acc[0][ni] = __builtin_amdgcn_mfma_f32_16x16x32_bf16(af, bfr[ni], acc[0][ni], 0, 0, 0);
    __syncthreads();
  }
#pragma unroll
  for (int ni = 0; ni < 4; ++ni) {
    int col = n0 + wn * 64 + ni * 16 + fr;
    float bv = fcb[col];
#pragma unroll
    for (int j = 0; j < 4; ++j) {
      int rowm = (wm == 0 ? 0 : 16) + fq * 4 + j;
      float val = tanhf(acc[0][ni][j] + bv);
      sf32[(size_t)rowm * 512 + col] = val;
      sbf[(size_t)rowm * 512 + col] = f2bf(val);
    }
  }
}

// Merged Gi precompute: z=0 encf, z=1 encb, z=2 dec (12 x-tiles).
__global__ __launch_bounds__(256) void gemm_gi(
    const unsigned short* __restrict__ xbf, const unsigned short* __restrict__ ebf,
    const float* __restrict__ encfW, const float* __restrict__ encbW,
    const float* __restrict__ decWih,
    const float* __restrict__ bihF, const float* __restrict__ bihB,
    const float* __restrict__ bihD,
    float* __restrict__ Gif, float* __restrict__ Gib, float* __restrict__ Gie) {
  const int z = blockIdx.z;
  const unsigned short* A;
  const float* B;
  const float* bias;
  float* C;
  int ldb, Mvalid;
  if (z == 0) { A = xbf; B = encfW; ldb = 512; bias = bihF; C = Gif; Mvalid = 2048; }
  else if (z == 1) { A = xbf; B = encbW; ldb = 512; bias = bihB; C = Gib; Mvalid = 2048; }
  else {
    if (blockIdx.x >= 12) return;
    A = ebf; B = decWih; ldb = 1536; bias = bihD; C = Gie; Mvalid = 1536;
  }
  gemm_body<true, false, false>(A, 512, B, ldb, 0, bias, C, 1536, 512, Mvalid, 0,
                                blockIdx.x * 128, blockIdx.y * 128);
}

// Merged attention projections: z=0 epf (4 y-tiles), z=1 EP2b (12 y-tiles).
__global__ __launch_bounds__(256) void gemm_ep(
    const unsigned short* __restrict__ ebo,
    const float* __restrict__ attnW, const float* __restrict__ decWih,
    unsigned short* __restrict__ epf, unsigned short* __restrict__ EP2b) {
  const int z = blockIdx.z;
  if (z == 0 && blockIdx.y >= 4) return;
  if (z == 0)
    gemm_body<true, false, true>(ebo, 1024, attnW, 1536, 512, nullptr, epf, 512,
                                 1024, 2048, 0, blockIdx.x * 128, blockIdx.y * 128);
  else
    gemm_body<true, false, true>(ebo, 1024, decWih, 1536, 512, nullptr, EP2b, 1536,
                                 1024, 2048, 0, blockIdx.x * 128, blockIdx.y * 128);
}

// Output projection, 3-buffer counted-vmcnt pipeline (T3/T4). 256x256 tile,
// BK=32, 8 waves. Per K-tile: vmcnt(4) -> 1 barrier -> 12 ds_read ->
// 32 MFMA (setprio) -> stage(kt+2). Loads stay in flight across barriers.
// Swizzle key ((r^(r>>2))&3)<<4 within 64B rows: residual 2-way = free.
__global__ __launch_bounds__(512, 1) void gemm_big8(
    const unsigned short* __restrict__ A,
    const unsigned short* __restrict__ B,
    const float* __restrict__ bias,
    float* __restrict__ C) {
  extern __shared__ char lds[];
  const int tid = threadIdx.x;
  const int w = tid >> 6, lane = tid & 63;
  int wg = blockIdx.x;
  {
    int x = wg & 7, i = wg >> 3;
    wg = (x < 6 ? x * 94 : 564 + (x - 6) * 93) + i;
  }
  const int m0 = (wg % 6) * 256, n0 = (wg / 6) * 256;
  const int wm = w >> 2, wn = w & 3;
  const int fr = lane & 15, fq = lane >> 4;
  const int srow = lane >> 2;                          // 0..15
  const int sch = (((lane & 3) ^ (srow & 3)) * 8);     // base inverse-swizzle

  // stage tile kt (32 cols) into buf c; 4 gl_lds per wave.
  auto stage = [&](int kt, int c) {
    char* LA = lds + c * 32768;
    char* LB = LA + 16384;
#pragma unroll
    for (int j = 0; j < 2; ++j) {
      int rb = w * 32 + j * 16;
      int rg = rb + srow;
      // key depends on full row index: ((r^(r>>2))&3); r = rg
      int ch = (((lane & 3) ^ ((rg ^ (rg >> 2)) & 3)) * 8);
      gl_lds16(A + (size_t)(m0 + rg) * 2048 + kt * 32 + ch,
               (unsigned short*)(LA + rb * 64));
      gl_lds16(B + (size_t)(n0 + rg) * 2048 + kt * 32 + ch,
               (unsigned short*)(LB + rb * 64));
    }
  };
  (void)sch;

  f32x4 acc[8][4];
#pragma unroll
  for (int mi = 0; mi < 8; ++mi)
#pragma unroll
    for (int ni = 0; ni < 4; ++ni) acc[mi][ni] = (f32x4){0.f, 0.f, 0.f, 0.f};

  stage(0, 0);
  stage(1, 1);

  int c = 0, cn = 2;
  for (int kt = 0; kt < 64; ++kt) {
    if (kt < 63) asm volatile("s_waitcnt vmcnt(4)" ::: "memory");
    else asm volatile("s_waitcnt vmcnt(0)" ::: "memory");
    __builtin_amdgcn_s_barrier();
    char* LA = lds + c * 32768;
    char* LB = LA + 16384;
    short8 bfrag[4], afrag[8];
#pragma unroll
    for (int ni = 0; ni < 4; ++ni) {
      int r = wn * 64 + ni * 16 + fr;
      int pb = r * 64 + ((fq * 16) ^ ((((r ^ (r >> 2)) & 3)) << 4));
      bfrag[ni] = *(const short8*)(LB + pb);
    }
#pragma unroll
    for (int mi = 0; mi < 8; ++mi) {
      int r = wm * 128 + mi * 16 + fr;
      int pb = r * 64 + ((fq * 16) ^ ((((r ^ (r >> 2)) & 3)) << 4));
      afrag[mi] = *(const short8*)(LA + pb);
    }
    __builtin_amdgcn_s_setprio(1);
#pragma unroll
    for (int mi = 0; mi < 8; ++mi)
#pragma unroll
      for (int ni = 0; ni < 4; ++ni)
        acc[mi][ni] = __builtin_amdgcn_mfma_f32_16x16x32_bf16(
            afrag[mi], bfrag[ni], acc[mi][ni], 0, 0, 0);
    __builtin_amdgcn_s_setprio(0);
    if (kt < 62) stage(kt + 2, cn);
    c = (c == 2) ? 0 : c + 1;
    cn = (cn == 2) ? 0 : cn + 1;
  }
#pragma unroll
  for (int mi = 0; mi < 8; ++mi)
#pragma unroll
    for (int ni = 0; ni < 4; ++ni) {
      int col = n0 + wn * 64 + ni * 16 + fr;
      float bv = bias[col];
#pragma unroll
      for (int j = 0; j < 4; ++j) {
        int row = m0 + wm * 128 + mi * 16 + fq * 4 + j;
        if (row < 1504) C[(size_t)(row + 32) * 32000 + col] = acc[mi][ni][j] + bv;
      }
    }
}

// One encoder GRU step, both directions. Blocks 0..31: dir=blk>>4, 32-d slice.
// Blocks 32..231: piggyback out_W f32->bf16 conversion (idle-CU work).
__global__ __launch_bounds__(512) void enc_step(
    const float* __restrict__ Gif, const float* __restrict__ Gib,
    const unsigned short* __restrict__ whFbf, const unsigned short* __restrict__ whBbf,
    const float* __restrict__ bhhF, const float* __restrict__ bhhB,
    unsigned short* __restrict__ hbf,
    float* __restrict__ hf32,
    unsigned short* __restrict__ ebo,
    float* __restrict__ hcat,
    const float* __restrict__ outW, unsigned short* __restrict__ outWbf, int nCvt,
    int t) {
  const int blk = blockIdx.x, tid = threadIdx.x;
  if (blk >= 32) {
    if (blk - 32 < nCvt) {
      size_t base4 = ((size_t)t * nCvt + (blk - 32)) * 1280;
      for (int i = tid; i < 1280; i += 512) {
        float4 v = ((const float4*)outW)[base4 + i];
        unsigned short* d = outWbf + (base4 + i) * 4;
        d[0] = f2bf(v.x); d[1] = f2bf(v.y); d[2] = f2bf(v.z); d[3] = f2bf(v.w);
      }
    }
    return;
  }
  const int dir = blk >> 4, slice = blk & 15, D0 = slice * 32;
  const unsigned short* Wbf = dir ? whBbf : whFbf;
  const float* Gi = dir ? Gib : Gif;
  const float* bhh = dir ? bhhB : bhhF;
  __shared__ __align__(16) unsigned short hlds[32 * 520];
  __shared__ __align__(16) float gl[96 * 33];
  const unsigned short* hb = hbf + dir * 32768 + (t & 1) * 16384;
  for (int c = tid; c < 32 * 64; c += 512) {
    int r = c >> 6, seg = c & 63;
    *(short8*)(hlds + r * 520 + seg * 8) = *(const short8*)(hb + r * 512 + seg * 8);
  }
  __syncthreads();
  const int w = tid >> 6, lane = tid & 63, fr = lane & 15, fq = lane >> 4;
  if (w < 6) {
    int row = w * 16 + fr;
    int gr = (row >> 5) * 512 + D0 + (row & 31);
    const unsigned short* wrow = Wbf + (size_t)gr * 512;
    f32x4 acc0 = {0.f, 0.f, 0.f, 0.f}, acc1 = {0.f, 0.f, 0.f, 0.f};
#pragma unroll
    for (int k0 = 0; k0 < 512; k0 += 32) {
      short8 bq = *(const short8*)(wrow + k0 + fq * 8);
      short8 a0 = *(const short8*)(hlds + fr * 520 + k0 + fq * 8);
      short8 a1 = *(const short8*)(hlds + (16 + fr) * 520 + k0 + fq * 8);
      acc0 = __builtin_amdgcn_mfma_f32_16x16x32_bf16(a0, bq, acc0, 0, 0, 0);
      acc1 = __builtin_amdgcn_mfma_f32_16x16x32_bf16(a1, bq, acc1, 0, 0, 0);
    }
#pragma unroll
    for (int j = 0; j < 4; ++j) {
      gl[row * 33 + fq * 4 + j] = acc0[j];
      gl[row * 33 + 16 + fq * 4 + j] = acc1[j];
    }
  }
  __syncthreads();
  const int srow = dir ? 63 - t : t;
  unsigned short* hnb = hbf + dir * 32768 + ((t + 1) & 1) * 16384;
  const float* hcur = hf32 + dir * 32768 + (t & 1) * 16384;
  float* hnf = hf32 + dir * 32768 + ((t + 1) & 1) * 16384;
#pragma unroll
  for (int rep = 0; rep < 2; ++rep) {
    int idx = rep * 512 + tid, b = idx >> 5, dl = idx & 31, d = D0 + dl;
    float ar = gl[dl * 33 + b] + bhh[d];
    float az = gl[(32 + dl) * 33 + b] + bhh[512 + d];
    float an = gl[(64 + dl) * 33 + b] + bhh[1024 + d];
    const float* gi = Gi + ((size_t)srow * 32 + b) * 1536;
    float r = sigm_fast(gi[d] + ar);
    float z = sigm_fast(gi[512 + d] + az);
    float n = tanh_fast(gi[1024 + d] + r * an);
    float h2 = (1.f - z) * n + z * hcur[b * 512 + d];
    hnb[b * 512 + d] = f2bf(h2);
    hnf[b * 512 + d] = h2;
    ebo[((size_t)b * 64 + srow) * 1024 + (size_t)dir * 512 + d] = f2bf(h2);
    if (t == 63) hcat[(size_t)b * 1024 + (size_t)dir * 512 + d] = h2;
  }
}

// Decoder step part 1: gout[b][n] = s_t[b] . Wcat[n] (+decBhh for n>=512).
__global__ __launch_bounds__(512) void dec_proj(
    const unsigned short* __restrict__ Wcat, const float* __restrict__ decBhh,
    const unsigned short* __restrict__ sbf, float* __restrict__ gout, int t) {
  const int g = blockIdx.x, tid = threadIdx.x;
  __shared__ __align__(16) unsigned short slds[32 * 520];
  const unsigned short* sb = sbf + (t & 1) * 16384;
  for (int c = tid; c < 32 * 64; c += 512) {
    int r = c >> 6, seg = c & 63;
    *(short8*)(slds + r * 520 + seg * 8) = *(const short8*)(sb + r * 512 + seg * 8);
  }
  __syncthreads();
  const int w = tid >> 6, lane = tid & 63, fr = lane & 15, fq = lane >> 4;
  const int mt = w >> 2, nt = w & 3;
  int rc = g * 64 + nt * 16 + fr;
  const unsigned short* wrow = Wcat + (size_t)rc * 512;
  f32x4 acc = {0.f, 0.f, 0.f, 0.f};
#pragma unroll
  for (int k0 = 0; k0 < 512; k0 += 32) {
    short8 a = *(const short8*)(slds + (mt * 16 + fr) * 520 + k0 + fq * 8);
    short8 bq = *(const short8*)(wrow + k0 + fq * 8);
    acc = __builtin_amdgcn_mfma_f32_16x16x32_bf16(a, bq, acc, 0, 0, 0);
  }
  float bv = rc < 512 ? 0.f : decBhh[rc - 512];
#pragma unroll
  for (int j = 0; j < 4; ++j)
    gout[(size_t)(mt * 16 + fq * 4 + j) * 2048 + rc] = acc[j] + bv;
}

// Decoder step part 2: scores, softmax, context, gic, gates. One block per
// batch. Phase C vectorized (u32 paired bf16 loads, s-split + LDS combine).
__global__ __launch_bounds__(512) void dec_attn(
    const float* __restrict__ attnV,
    const unsigned short* __restrict__ epf,
    const u32* __restrict__ eb32,
    const u32* __restrict__ ep232,
    const float* __restrict__ Gie,
    const float* __restrict__ gout,
    unsigned short* __restrict__ sbf, float* __restrict__ sf32,
    unsigned short* __restrict__ Zbf, int t) {
  const int b = blockIdx.x, tid = threadIdx.x;
  __shared__ __align__(16) float gout_f[2048];
  __shared__ float raw[64], aaw[64];
  __shared__ float vlds[512];
  __shared__ __align__(8) float2 part[5][256];
  vlds[tid] = attnV[tid];
  *(float4*)(gout_f + tid * 4) = *(const float4*)(gout + (size_t)b * 2048 + tid * 4);
  __syncthreads();
  const int s_i = tid >> 3, l8 = tid & 7;
  {
    float part1 = 0.f;
    const float* gp = gout_f + l8 * 64;
    const unsigned short* ep = epf + ((size_t)b * 64 + s_i) * 512 + l8 * 64;
    const float* vv = vlds + l8 * 64;
#pragma unroll
    for (int jc = 0; jc < 8; ++jc) {
      short8 e8 = *(const short8*)(ep + jc * 8);
      float4 g0 = *(const float4*)(gp + jc * 8);
      float4 g1 = *(const float4*)(gp + jc * 8 + 4);
      float4 v0 = *(const float4*)(vv + jc * 8);
      float4 v1 = *(const float4*)(vv + jc * 8 + 4);
      part1 += tanh_fast(g0.x + bf2f((unsigned short)e8[0])) * v0.x;
      part1 += tanh_fast(g0.y + bf2f((unsigned short)e8[1])) * v0.y;
      part1 += tanh_fast(g0.z + bf2f((unsigned short)e8[2])) * v0.z;
      part1 += tanh_fast(g0.w + bf2f((unsigned short)e8[3])) * v0.w;
      part1 += tanh_fast(g1.x + bf2f((unsigned short)e8[4])) * v1.x;
      part1 += tanh_fast(g1.y + bf2f((unsigned short)e8[5])) * v1.y;
      part1 += tanh_fast(g1.z + bf2f((unsigned short)e8[6])) * v1.z;
      part1 += tanh_fast(g1.w + bf2f((unsigned short)e8[7])) * v1.w;
    }
    part1 += __shfl_xor(part1, 1);
    part1 += __shfl_xor(part1, 2);
    part1 += __shfl_xor(part1, 4);
    if (l8 == 0) raw[s_i] = part1;
  }
  __syncthreads();
  if (tid < 64) {
    float x = raw[tid];
    float m = x;
#pragma unroll
    for (int k = 1; k < 64; k <<= 1) m = fmaxf(m, __shfl_xor(m, k));
    float e = __expf(x - m);
    float s = e;
#pragma unroll
    for (int k = 1; k < 64; k <<= 1) s += __shfl_xor(s, k);
    aaw[tid] = e * __builtin_amdgcn_rcpf(s);
  }
  __syncthreads();
  {
    const int cp = tid & 255, sh = tid >> 8;
    const u32* eb = eb32 + (size_t)b * 32768 + cp;
    const u32* e2 = ep232 + (size_t)b * 49152 + cp;
    float p0x = 0.f, p0y = 0.f, p1x = 0.f, p1y = 0.f, p2x = 0.f, p2y = 0.f;
    float p3x = 0.f, p3y = 0.f, p4x = 0.f, p4y = 0.f;
    const int sbase = sh * 32;
#pragma unroll 4
    for (int i = 0; i < 32; ++i) {
      int s2 = sbase + i;
      float a = aaw[s2];
      u32 v0 = eb[(size_t)s2 * 512];
      u32 v1 = eb[(size_t)s2 * 512 + 256];
      u32 v2 = e2[(size_t)s2 * 768];
      u32 v3 = e2[(size_t)s2 * 768 + 256];
      u32 v4 = e2[(size_t)s2 * 768 + 512];
      p0x += a * bflo(v0); p0y += a * bfhi(v0);
      p1x += a * bflo(v1); p1y += a * bfhi(v1);
      p2x += a * bflo(v2); p2y += a * bfhi(v2);
      p3x += a * bflo(v3); p3y += a * bfhi(v3);
      p4x += a * bflo(v4); p4y += a * bfhi(v4);
    }
    if (sh == 0) {
      part[0][cp] = make_float2(p0x, p0y);
      part[1][cp] = make_float2(p1x, p1y);
      part[2][cp] = make_float2(p2x, p2y);
      part[3][cp] = make_float2(p3x, p3y);
      part[4][cp] = make_float2(p4x, p4y);
    }
    __syncthreads();
    if (sh == 1) {
      part[0][cp].x += p0x; part[0][cp].y += p0y;
      part[1][cp].x += p1x; part[1][cp].y += p1y;
      part[2][cp].x += p2x; part[2][cp].y += p2y;
      part[3][cp].x += p3x; part[3][cp].y += p3y;
      part[4][cp].x += p4x; part[4][cp].y += p4y;
    }
  }
  __syncthreads();
  size_t zrow = ((size_t)t * 32 + b) * 2048;
  {
    int slot = tid >> 8, cp2 = tid & 255;
    float2 cpair = part[slot][cp2];
    u32 pk = (u32)f2bf(cpair.x) | ((u32)f2bf(cpair.y) << 16);
    *(u32*)(Zbf + zrow + 512 + (size_t)(slot * 256 + cp2) * 2) = pk;
  }
  {
    int hp = tid >> 1, odd = tid & 1;
    float g0a = odd ? part[2][hp].y : part[2][hp].x;
    float g1a = odd ? part[3][hp].y : part[3][hp].x;
    float g2a = odd ? part[4][hp].y : part[4][hp].x;
    const float* gie = Gie + ((size_t)t * 32 + b) * 1536;
    float sprev = sf32[(t & 1) * 16384 + b * 512 + tid];
    float rr = sigm_fast(gie[tid] + g0a + gout_f[512 + tid]);
    float zz = sigm_fast(gie[512 + tid] + g1a + gout_f[1024 + tid]);
    float nn = tanh_fast(gie[1024 + tid] + g2a + rr * gout_f[1536 + tid]);
    float s2v = (1.f - zz) * nn + zz * sprev;
    sbf[((t + 1) & 1) * 16384 + b * 512 + tid] = f2bf(s2v);
    sf32[((t + 1) & 1) * 16384 + b * 512 + tid] = s2v;
    Zbf[zrow + tid] = f2bf(s2v);
  }
}

extern "C" void kernel_launch(void* const* d_in, const int* in_sizes, int n_in,
                              void* d_out, int out_size, void* d_ws, size_t ws_size,
                              hipStream_t stream) {
  (void)in_sizes; (void)n_in; (void)out_size;
  const int* src = (const int*)d_in[0];
  const int* trg = (const int*)d_in[1];
  const float* emb = (const float*)d_in[2];
  const float* encf_Wih = (const float*)d_in[3];
  const float* encf_Whh = (const float*)d_in[4];
  const float* encf_bih = (const float*)d_in[5];
  const float* encf_bhh = (const float*)d_in[6];
  const float* encb_Wih = (const float*)d_in[7];
  const float* encb_Whh = (const float*)d_in[8];
  const float* encb_bih = (const float*)d_in[9];
  const float* encb_bhh = (const float*)d_in[10];
  const float* fc_W = (const float*)d_in[11];
  const float* fc_b = (const float*)d_in[12];
  const float* attn_W = (const float*)d_in[13];
  const float* attn_v = (const float*)d_in[14];
  const float* dec_Wih = (const float*)d_in[15];
  const float* dec_Whh = (const float*)d_in[16];
  const float* dec_bih = (const float*)d_in[17];
  const float* dec_bhh = (const float*)d_in[18];
  const float* out_W = (const float*)d_in[19];
  const float* out_b = (const float*)d_in[20];
  float* out = (float*)d_out;

  char* p = (char*)d_ws;
  size_t off = 0;
  auto alloc = [&](size_t bytes) {
    void* r = p + off;
    off = (off + bytes + 255) & ~(size_t)255;
    return r;
  };
  unsigned short* xbf = (unsigned short*)alloc((size_t)2048 * 512 * 2);
  unsigned short* ebf = (unsigned short*)alloc((size_t)1536 * 512 * 2);
  unsigned short* Zbf = (unsigned short*)alloc((size_t)1536 * 2048 * 2);
  float* Gif = (float*)alloc((size_t)2048 * 1536 * 4);
  float* Gib = (float*)alloc((size_t)2048 * 1536 * 4);
  float* Gie = (float*)alloc((size_t)1536 * 1536 * 4);
  unsigned short* ebo = (unsigned short*)alloc((size_t)2048 * 1024 * 2);
  unsigned short* epf = (unsigned short*)alloc((size_t)2048 * 512 * 2);
  unsigned short* EP2b = (unsigned short*)alloc((size_t)2048 * 1536 * 2);
  unsigned short* whFbf = (unsigned short*)alloc((size_t)1536 * 512 * 2);
  unsigned short* whBbf = (unsigned short*)alloc((size_t)1536 * 512 * 2);
  unsigned short* Wcat = (unsigned short*)alloc((size_t)2048 * 512 * 2);
  unsigned short* hbf = (unsigned short*)alloc((size_t)2 * 2 * 32 * 512 * 2);
  float* hf32 = (float*)alloc((size_t)2 * 2 * 32 * 512 * 4);
  float* hcat = (float*)alloc((size_t)32 * 1024 * 4);
  unsigned short* sbf = (unsigned short*)alloc((size_t)2 * 32 * 512 * 2);
  float* sf32 = (float*)alloc((size_t)2 * 32 * 512 * 4);
  float* gout = (float*)alloc((size_t)32 * 2048 * 4);
  unsigned short* outWbf = (unsigned short*)alloc((size_t)32000 * 2048 * 2);
  const bool bigB = (off <= ws_size);

  prep_gather<<<8744, 128, 0, stream>>>(src, trg, emb, xbf, ebf, Zbf,
                                        out, hbf, hf32,
                                        encf_Whh, encb_Whh, attn_W, dec_Whh,
                                        whFbf, whBbf, Wcat);

  gemm_gi<<<dim3(16, 12, 3), 256, 0, stream>>>(
      xbf, ebf, encf_Wih, encb_Wih, dec_Wih, encf_bih, encb_bih, dec_bih,
      Gif, Gib, Gie);

  const int nCvt = bigB ? 200 : 0;
  for (int t = 0; t < 64; ++t)
    enc_step<<<32 + nCvt, 512, 0, stream>>>(Gif, Gib, whFbf, whBbf, encf_bhh, encb_bhh,
                                            hbf, hf32, ebo, hcat, out_W, outWbf, nCvt, t);

  gemm_fc<<<4, 256, 0, stream>>>(hcat, fc_W, fc_b, sf32, sbf);

  gemm_ep<<<dim3(16, 12, 2), 256, 0, stream>>>(ebo, attn_W, dec_Wih, epf, EP2b);

  for (int t = 0; t < 47; ++t) {
    dec_proj<<<32, 512, 0, stream>>>(Wcat, dec_bhh, sbf, gout, t);
    dec_attn<<<32, 512, 0, stream>>>(attn_v, epf, (const u32*)ebo, (const u32*)EP2b,
                                     Gie, gout, sbf, sf32, Zbf, t);
  }

  if (bigB) {
    hipFuncSetAttribute((const void*)gemm_big8,
                        hipFuncAttributeMaxDynamicSharedMemorySize, 98304);
    gemm_big8<<<750, 512, 98304, stream>>>(Zbf, outWbf, out_b, out);
  } else {
    gemm_kernel<true, false, false><<<dim3(12, 250), 256, 0, stream>>>(
        Zbf, 2048, out_W, 2048, 0, out_b, out, 32000, 2048, 1504, 32);
  }
}

// Round 17
// 1615.726 us; speedup vs baseline: 1.0143x; 1.0143x over previous
//
#include <hip/hip_runtime.h>
#include <stdint.h>
#include <stddef.h>

typedef __attribute__((ext_vector_type(8))) short short8;
typedef __attribute__((ext_vector_type(4))) float f32x4;
typedef unsigned int u32;

__device__ inline unsigned short f2bf(float f) {
  union { float f; uint32_t u; } v; v.f = f;
  uint32_t u = v.u;
  u += 0x7FFFu + ((u >> 16) & 1u);
  return (unsigned short)(u >> 16);
}
__device__ inline float bf2f(unsigned short h) {
  union { uint32_t u; float f; } v; v.u = ((uint32_t)h) << 16; return v.f;
}
__device__ inline float bflo(u32 v) {
  union { u32 u; float f; } x; x.u = v << 16; return x.f;
}
__device__ inline float bfhi(u32 v) {
  union { u32 u; float f; } x; x.u = v & 0xffff0000u; return x.f;
}
__device__ inline short8 pack8(float4 a, float4 b) {
  short8 r;
  r[0] = (short)f2bf(a.x); r[1] = (short)f2bf(a.y);
  r[2] = (short)f2bf(a.z); r[3] = (short)f2bf(a.w);
  r[4] = (short)f2bf(b.x); r[5] = (short)f2bf(b.y);
  r[6] = (short)f2bf(b.z); r[7] = (short)f2bf(b.w);
  return r;
}
__device__ inline float tanh_fast(float x) {
  float xc = fminf(fmaxf(x, -9.f), 9.f);
  float e = __expf(2.f * xc);
  return (e - 1.f) * __builtin_amdgcn_rcpf(e + 1.f);
}
__device__ inline float sigm_fast(float x) {
  float xc = fminf(fmaxf(x, -30.f), 30.f);
  return __builtin_amdgcn_rcpf(1.f + __expf(-xc));
}
// async global->LDS, 16 bytes per lane (wave-uniform LDS base + lane*16)
__device__ inline void gl_lds16(const unsigned short* g, unsigned short* l) {
  __builtin_amdgcn_global_load_lds(
      (const __attribute__((address_space(1))) u32*)g,
      (__attribute__((address_space(3))) u32*)l, 16, 0, 0);
}

// Gather + bf16-convert embeddings. Blocks 3584..3623 zero d_out rows 0..31
// and h state buffers; blocks 3624..8743 do the weight f32->bf16 conversions.
__global__ __launch_bounds__(128) void prep_gather(
    const int* __restrict__ src, const int* __restrict__ trg,
    const float* __restrict__ emb,
    unsigned short* __restrict__ xbf, unsigned short* __restrict__ ebf,
    unsigned short* __restrict__ Zbf,
    float* __restrict__ outZero,
    unsigned short* __restrict__ hbf,
    float* __restrict__ hf32,
    const float* __restrict__ encfW, const float* __restrict__ encbW,
    const float* __restrict__ attnW, const float* __restrict__ decWhh,
    unsigned short* __restrict__ whFbf, unsigned short* __restrict__ whBbf,
    unsigned short* __restrict__ Wcat) {
  int r = blockIdx.x, tid = threadIdx.x;
  if (r >= 3624) {
    if (tid >= 64) return;
    int q = r - 3624;
    int c = tid * 8;
    const float* s;
    unsigned short* d;
    if (q < 1536) { s = encfW + (size_t)q * 512 + c; d = whFbf + (size_t)q * 512 + c; }
    else if (q < 3072) { int u = q - 1536; s = encbW + (size_t)u * 512 + c; d = whBbf + (size_t)u * 512 + c; }
    else if (q < 3584) { int u = q - 3072; s = attnW + (size_t)u * 1536 + c; d = Wcat + (size_t)u * 512 + c; }
    else { int u = q - 3584; s = decWhh + (size_t)u * 512 + c; d = Wcat + (size_t)(u + 512) * 512 + c; }
    *(short8*)d = pack8(*(const float4*)s, *(const float4*)(s + 4));
    return;
  }
  if (r >= 3584) {
    int z = r - 3584;
    if (z < 32) {
      float4* dst = (float4*)(outZero + (size_t)z * 32000);
      for (int i = tid; i < 8000; i += 128) dst[i] = (float4){0.f, 0.f, 0.f, 0.f};
    } else if (z < 36) {
      float4* dst = (float4*)(hbf + (size_t)(z - 32) * 32768);
      for (int i = tid; i < 4096; i += 128) dst[i] = (float4){0.f, 0.f, 0.f, 0.f};
    } else if (z < 40) {
      float4* dst = (float4*)(hf32 + (size_t)(z - 36) * 32768);
      for (int i = tid; i < 8192; i += 128) dst[i] = (float4){0.f, 0.f, 0.f, 0.f};
    }
    return;
  }
  if (r < 2048) {
    int b = r & 31, s = r >> 5;
    int tok = src[b * 64 + s];
    const float* e = emb + (size_t)tok * 512;
    float4 v = *(const float4*)(e + tid * 4);
    unsigned short* dst = xbf + (size_t)r * 512 + tid * 4;
    dst[0] = f2bf(v.x); dst[1] = f2bf(v.y); dst[2] = f2bf(v.z); dst[3] = f2bf(v.w);
  } else {
    int rr = r - 2048;
    int t = rr >> 5, b = rr & 31;
    unsigned short* dst = ebf + (size_t)rr * 512 + tid * 4;
    if (t < 47) {
      int tok = trg[t * 32 + b];
      const float* e = emb + (size_t)tok * 512;
      float4 v = *(const float4*)(e + tid * 4);
      unsigned short q0 = f2bf(v.x), q1 = f2bf(v.y), q2 = f2bf(v.z), q3 = f2bf(v.w);
      dst[0] = q0; dst[1] = q1; dst[2] = q2; dst[3] = q3;
      unsigned short* zd = Zbf + (size_t)rr * 2048 + 1536 + tid * 4;
      zd[0] = q0; zd[1] = q1; zd[2] = q2; zd[3] = q3;
    } else {
      dst[0] = 0; dst[1] = 0; dst[2] = 0; dst[3] = 0;
    }
  }
}

// Shared GEMM body: C[m,n] = sum_k A[m,k]*B[n,k] (+bias[n]).
template <bool ABF, bool BBF, bool WBF>
__device__ inline void gemm_body(
    const void* __restrict__ Av, int lda,
    const void* __restrict__ Bv, int ldb, int bco,
    const float* __restrict__ bias,
    void* __restrict__ Cv, int ldc,
    int K, int Mvalid, int row_off, int m0, int n0) {
  __shared__ __align__(16) unsigned short As[128 * 32];
  __shared__ __align__(16) unsigned short Bs[128 * 32];
  const int tid = threadIdx.x;
  const int w = tid >> 6, lane = tid & 63;
  const int wm = w >> 1, wn = w & 1;
  const int fr = lane & 15, fq = lane >> 4;
  f32x4 acc[4][4];
#pragma unroll
  for (int mi = 0; mi < 4; ++mi)
#pragma unroll
    for (int ni = 0; ni < 4; ++ni) acc[mi][ni] = (f32x4){0.f, 0.f, 0.f, 0.f};
  for (int k0 = 0; k0 < K; k0 += 32) {
#pragma unroll
    for (int p = 0; p < 2; ++p) {
      int idx = p * 256 + tid;
      int row = idx >> 2, seg = idx & 3;
      if (ABF) {
        const unsigned short* Ab = (const unsigned short*)Av;
        *(short8*)(As + row * 32 + seg * 8) =
            *(const short8*)(Ab + (size_t)(m0 + row) * lda + k0 + seg * 8);
      } else {
        const float* Af = (const float*)Av;
        const float* ap = Af + (size_t)(m0 + row) * lda + k0 + seg * 8;
        *(short8*)(As + row * 32 + seg * 8) = pack8(*(const float4*)ap, *(const float4*)(ap + 4));
      }
      if (BBF) {
        const unsigned short* Bb = (const unsigned short*)Bv;
        *(short8*)(Bs + row * 32 + seg * 8) =
            *(const short8*)(Bb + (size_t)(n0 + row) * ldb + bco + k0 + seg * 8);
      } else {
        const float* Bf = (const float*)Bv;
        const float* bp = Bf + (size_t)(n0 + row) * ldb + bco + k0 + seg * 8;
        *(short8*)(Bs + row * 32 + seg * 8) = pack8(*(const float4*)bp, *(const float4*)(bp + 4));
      }
    }
    __syncthreads();
    short8 af[4], bfr[4];
#pragma unroll
    for (int mi = 0; mi < 4; ++mi)
      af[mi] = *(const short8*)(As + (wm * 64 + mi * 16 + fr) * 32 + fq * 8);
#pragma unroll
    for (int ni = 0; ni < 4; ++ni)
      bfr[ni] = *(const short8*)(Bs + (wn * 64 + ni * 16 + fr) * 32 + fq * 8);
#pragma unroll
    for (int mi = 0; mi < 4; ++mi)
#pragma unroll
      for (int ni = 0; ni < 4; ++ni)
        acc[mi][ni] = __builtin_amdgcn_mfma_f32_16x16x32_bf16(af[mi], bfr[ni], acc[mi][ni], 0, 0, 0);
    __syncthreads();
  }
#pragma unroll
  for (int mi = 0; mi < 4; ++mi)
#pragma unroll
    for (int ni = 0; ni < 4; ++ni) {
      int col = n0 + wn * 64 + ni * 16 + fr;
      float bv = bias ? bias[col] : 0.f;
#pragma unroll
      for (int j = 0; j < 4; ++j) {
        int rowm = m0 + wm * 64 + mi * 16 + fq * 4 + j;
        if (rowm < Mvalid) {
          float val = acc[mi][ni][j] + bv;
          if (WBF)
            ((unsigned short*)Cv)[(size_t)(rowm + row_off) * ldc + col] = f2bf(val);
          else
            ((float*)Cv)[(size_t)(rowm + row_off) * ldc + col] = val;
        }
      }
    }
}

template <bool ABF, bool BBF, bool WBF>
__global__ __launch_bounds__(256) void gemm_kernel(
    const void* __restrict__ Av, int lda,
    const void* __restrict__ Bv, int ldb, int bco,
    const float* __restrict__ bias,
    void* __restrict__ Cv, int ldc,
    int K, int Mvalid, int row_off) {
  gemm_body<ABF, BBF, WBF>(Av, lda, Bv, ldb, bco, bias, Cv, ldc, K, Mvalid,
                           row_off, blockIdx.x * 128, blockIdx.y * 128);
}

// fc GEMM with tanh epilogue: s0 = tanh(hcat @ fc_W^T + fc_b).
__global__ __launch_bounds__(256) void gemm_fc(
    const float* __restrict__ hcat, const float* __restrict__ fcW,
    const float* __restrict__ fcb,
    float* __restrict__ sf32, unsigned short* __restrict__ sbf) {
  __shared__ __align__(16) unsigned short As[128 * 32];
  __shared__ __align__(16) unsigned short Bs[128 * 32];
  const int tid = threadIdx.x;
  const int n0 = blockIdx.x * 128;
  const int w = tid >> 6, lane = tid & 63;
  const int wm = w >> 1, wn = w & 1;
  const int fr = lane & 15, fq = lane >> 4;
  f32x4 acc[4][4];
#pragma unroll
  for (int mi = 0; mi < 4; ++mi)
#pragma unroll
    for (int ni = 0; ni < 4; ++ni) acc[mi][ni] = (f32x4){0.f, 0.f, 0.f, 0.f};
  for (int k0 = 0; k0 < 1024; k0 += 32) {
#pragma unroll
    for (int p = 0; p < 2; ++p) {
      int idx = p * 256 + tid;
      int row = idx >> 2, seg = idx & 3;
      if (row < 32) {
        const float* ap = hcat + (size_t)row * 1024 + k0 + seg * 8;
        *(short8*)(As + row * 32 + seg * 8) = pack8(*(const float4*)ap, *(const float4*)(ap + 4));
      }
      const float* bp = fcW + (size_t)(n0 + row) * 1024 + k0 + seg * 8;
      *(short8*)(Bs + row * 32 + seg * 8) = pack8(*(const float4*)bp, *(const float4*)(bp + 4));
    }
    __syncthreads();
    short8 af, bfr[4];
    af = *(const short8*)(As + ((wm == 0 ? fr : fr + 16)) * 32 + fq * 8);
#pragma unroll
    for (int ni = 0; ni < 4; ++ni)
      bfr[ni] = *(const short8*)(Bs + (wn * 64 + ni * 16 + fr) * 32 + fq * 8);
#pragma unroll
    for (int ni = 0; ni < 4; ++ni)
      acc[0][ni] = __builtin_amdgcn_mfma_f32_16x16x32_bf16(af, bfr[ni], acc[0][ni], 0, 0, 0);
    __syncthreads();
  }
#pragma unroll
  for (int ni = 0; ni < 4; ++ni) {
    int col = n0 + wn * 64 + ni * 16 + fr;
    float bv = fcb[col];
#pragma unroll
    for (int j = 0; j < 4; ++j) {
      int rowm = (wm == 0 ? 0 : 16) + fq * 4 + j;
      float val = tanhf(acc[0][ni][j] + bv);
      sf32[(size_t)rowm * 512 + col] = val;
      sbf[(size_t)rowm * 512 + col] = f2bf(val);
    }
  }
}

// Merged Gi precompute: z=0 encf, z=1 encb, z=2 dec (12 x-tiles).
__global__ __launch_bounds__(256) void gemm_gi(
    const unsigned short* __restrict__ xbf, const unsigned short* __restrict__ ebf,
    const float* __restrict__ encfW, const float* __restrict__ encbW,
    const float* __restrict__ decWih,
    const float* __restrict__ bihF, const float* __restrict__ bihB,
    const float* __restrict__ bihD,
    float* __restrict__ Gif, float* __restrict__ Gib, float* __restrict__ Gie) {
  const int z = blockIdx.z;
  const unsigned short* A;
  const float* B;
  const float* bias;
  float* C;
  int ldb, Mvalid;
  if (z == 0) { A = xbf; B = encfW; ldb = 512; bias = bihF; C = Gif; Mvalid = 2048; }
  else if (z == 1) { A = xbf; B = encbW; ldb = 512; bias = bihB; C = Gib; Mvalid = 2048; }
  else {
    if (blockIdx.x >= 12) return;
    A = ebf; B = decWih; ldb = 1536; bias = bihD; C = Gie; Mvalid = 1536;
  }
  gemm_body<true, false, false>(A, 512, B, ldb, 0, bias, C, 1536, 512, Mvalid, 0,
                                blockIdx.x * 128, blockIdx.y * 128);
}

// Merged attention projections: z=0 epf (4 y-tiles), z=1 EP2b (12 y-tiles).
__global__ __launch_bounds__(256) void gemm_ep(
    const unsigned short* __restrict__ ebo,
    const float* __restrict__ attnW, const float* __restrict__ decWih,
    unsigned short* __restrict__ epf, unsigned short* __restrict__ EP2b) {
  const int z = blockIdx.z;
  if (z == 0 && blockIdx.y >= 4) return;
  if (z == 0)
    gemm_body<true, false, true>(ebo, 1024, attnW, 1536, 512, nullptr, epf, 512,
                                 1024, 2048, 0, blockIdx.x * 128, blockIdx.y * 128);
  else
    gemm_body<true, false, true>(ebo, 1024, decWih, 1536, 512, nullptr, EP2b, 1536,
                                 1024, 2048, 0, blockIdx.x * 128, blockIdx.y * 128);
}

// Output projection, 8-phase 256x256 (r15: conflict-free ((r&7)<<4) swizzle,
// XCD-swizzled grid, double-buffered 128KiB LDS).
__global__ __launch_bounds__(512, 1) void gemm_big8(
    const unsigned short* __restrict__ A,
    const unsigned short* __restrict__ B,
    const float* __restrict__ bias,
    float* __restrict__ C) {
  extern __shared__ char lds[];
  char* LA = lds;
  char* LB = lds + 65536;
  const int tid = threadIdx.x;
  const int w = tid >> 6, lane = tid & 63;
  int wg = blockIdx.x;
  {
    int x = wg & 7, i = wg >> 3;
    wg = (x < 6 ? x * 94 : 564 + (x - 6) * 93) + i;
  }
  const int m0 = (wg % 6) * 256, n0 = (wg / 6) * 256;
  const int wm = w >> 2, wn = w & 3;
  const int fr = lane & 15, fq = lane >> 4;

  auto stage = [&](const unsigned short* G, char* L, int rowbase, int kt, int h, int c) {
#pragma unroll
    for (int j = 0; j < 2; ++j) {
      int pbh = j * 8192 + w * 1024;
      int pl = pbh + lane * 16;
      int lb = pl ^ (((pl >> 7) & 7) << 4);
      int rl = lb >> 7, ch = (lb >> 4) & 7;
      gl_lds16(G + (size_t)(rowbase + h * 128 + rl) * 2048 + kt * 64 + ch * 8,
               (unsigned short*)(L + c * 32768 + h * 16384 + pbh));
    }
  };

  f32x4 acc[8][4];
#pragma unroll
  for (int mi = 0; mi < 8; ++mi)
#pragma unroll
    for (int ni = 0; ni < 4; ++ni) acc[mi][ni] = (f32x4){0.f, 0.f, 0.f, 0.f};

  stage(A, LA, m0, 0, 0, 0); stage(B, LB, n0, 0, 0, 0);
  stage(A, LA, m0, 0, 1, 0); stage(B, LB, n0, 0, 1, 0);
  asm volatile("s_waitcnt vmcnt(0)" ::: "memory");
  __builtin_amdgcn_s_barrier();

  short8 bfrag[8];
  for (int kt = 0; kt < 32; ++kt) {
    const int c = kt & 1;
    char* Abuf = LA + c * 32768;
    char* Bbuf = LB + c * 32768;
#pragma unroll
    for (int p = 0; p < 4; ++p) {
      if (kt < 31) {
        if (p == 0) {
          stage(A, LA, m0, kt + 1, 0, c ^ 1);
          stage(B, LB, n0, kt + 1, 0, c ^ 1);
        } else if (p == 1) {
          stage(A, LA, m0, kt + 1, 1, c ^ 1);
          stage(B, LB, n0, kt + 1, 1, c ^ 1);
        }
      }
      if (p == 0) {
#pragma unroll
        for (int ni = 0; ni < 4; ++ni)
#pragma unroll
          for (int ks = 0; ks < 2; ++ks) {
            int n = wn * 64 + ni * 16 + fr;
            int h = n >> 7, nl = n & 127;
            int lb = nl * 128 + ks * 64 + fq * 16;
            int pb = lb ^ (((lb >> 7) & 7) << 4);
            bfrag[ni * 2 + ks] = *(const short8*)(Bbuf + h * 16384 + pb);
          }
      }
      short8 afrag[4];
#pragma unroll
      for (int q = 0; q < 2; ++q)
#pragma unroll
        for (int ks = 0; ks < 2; ++ks) {
          int r = wm * 128 + (2 * p + q) * 16 + fr;
          int h = r >> 7, rl = r & 127;
          int lb = rl * 128 + ks * 64 + fq * 16;
          int pb = lb ^ (((lb >> 7) & 7) << 4);
          afrag[q * 2 + ks] = *(const short8*)(Abuf + h * 16384 + pb);
        }
      __builtin_amdgcn_s_setprio(1);
#pragma unroll
      for (int q = 0; q < 2; ++q)
#pragma unroll
        for (int ni = 0; ni < 4; ++ni)
#pragma unroll
          for (int ks = 0; ks < 2; ++ks)
            acc[2 * p + q][ni] = __builtin_amdgcn_mfma_f32_16x16x32_bf16(
                afrag[q * 2 + ks], bfrag[ni * 2 + ks], acc[2 * p + q][ni], 0, 0, 0);
      __builtin_amdgcn_s_setprio(0);
      if (p == 3) asm volatile("s_waitcnt vmcnt(0)" ::: "memory");
      __builtin_amdgcn_s_barrier();
    }
  }
#pragma unroll
  for (int mi = 0; mi < 8; ++mi)
#pragma unroll
    for (int ni = 0; ni < 4; ++ni) {
      int col = n0 + wn * 64 + ni * 16 + fr;
      float bv = bias[col];
#pragma unroll
      for (int j = 0; j < 4; ++j) {
        int row = m0 + wm * 128 + mi * 16 + fq * 4 + j;
        if (row < 1504) C[(size_t)(row + 32) * 32000 + col] = acc[mi][ni][j] + bv;
      }
    }
}

// One encoder GRU step, both directions. Blocks 0..31: dir=blk>>4, 32-d slice.
// Blocks 32..231: piggyback out_W f32->bf16 conversion (idle-CU work).
__global__ __launch_bounds__(512) void enc_step(
    const float* __restrict__ Gif, const float* __restrict__ Gib,
    const unsigned short* __restrict__ whFbf, const unsigned short* __restrict__ whBbf,
    const float* __restrict__ bhhF, const float* __restrict__ bhhB,
    unsigned short* __restrict__ hbf,
    float* __restrict__ hf32,
    unsigned short* __restrict__ ebo,
    float* __restrict__ hcat,
    const float* __restrict__ outW, unsigned short* __restrict__ outWbf, int nCvt,
    int t) {
  const int blk = blockIdx.x, tid = threadIdx.x;
  if (blk >= 32) {
    if (blk - 32 < nCvt) {
      size_t base4 = ((size_t)t * nCvt + (blk - 32)) * 1280;
      for (int i = tid; i < 1280; i += 512) {
        float4 v = ((const float4*)outW)[base4 + i];
        unsigned short* d = outWbf + (base4 + i) * 4;
        d[0] = f2bf(v.x); d[1] = f2bf(v.y); d[2] = f2bf(v.z); d[3] = f2bf(v.w);
      }
    }
    return;
  }
  const int dir = blk >> 4, slice = blk & 15, D0 = slice * 32;
  const unsigned short* Wbf = dir ? whBbf : whFbf;
  const float* Gi = dir ? Gib : Gif;
  const float* bhh = dir ? bhhB : bhhF;
  __shared__ __align__(16) unsigned short hlds[32 * 520];
  __shared__ __align__(16) float gl[96 * 33];
  const unsigned short* hb = hbf + dir * 32768 + (t & 1) * 16384;
  for (int c = tid; c < 32 * 64; c += 512) {
    int r = c >> 6, seg = c & 63;
    *(short8*)(hlds + r * 520 + seg * 8) = *(const short8*)(hb + r * 512 + seg * 8);
  }
  __syncthreads();
  const int w = tid >> 6, lane = tid & 63, fr = lane & 15, fq = lane >> 4;
  if (w < 6) {
    int row = w * 16 + fr;
    int gr = (row >> 5) * 512 + D0 + (row & 31);
    const unsigned short* wrow = Wbf + (size_t)gr * 512;
    f32x4 acc0 = {0.f, 0.f, 0.f, 0.f}, acc1 = {0.f, 0.f, 0.f, 0.f};
#pragma unroll
    for (int k0 = 0; k0 < 512; k0 += 32) {
      short8 bq = *(const short8*)(wrow + k0 + fq * 8);
      short8 a0 = *(const short8*)(hlds + fr * 520 + k0 + fq * 8);
      short8 a1 = *(const short8*)(hlds + (16 + fr) * 520 + k0 + fq * 8);
      acc0 = __builtin_amdgcn_mfma_f32_16x16x32_bf16(a0, bq, acc0, 0, 0, 0);
      acc1 = __builtin_amdgcn_mfma_f32_16x16x32_bf16(a1, bq, acc1, 0, 0, 0);
    }
#pragma unroll
    for (int j = 0; j < 4; ++j) {
      gl[row * 33 + fq * 4 + j] = acc0[j];
      gl[row * 33 + 16 + fq * 4 + j] = acc1[j];
    }
  }
  __syncthreads();
  const int srow = dir ? 63 - t : t;
  unsigned short* hnb = hbf + dir * 32768 + ((t + 1) & 1) * 16384;
  const float* hcur = hf32 + dir * 32768 + (t & 1) * 16384;
  float* hnf = hf32 + dir * 32768 + ((t + 1) & 1) * 16384;
#pragma unroll
  for (int rep = 0; rep < 2; ++rep) {
    int idx = rep * 512 + tid, b = idx >> 5, dl = idx & 31, d = D0 + dl;
    float ar = gl[dl * 33 + b] + bhh[d];
    float az = gl[(32 + dl) * 33 + b] + bhh[512 + d];
    float an = gl[(64 + dl) * 33 + b] + bhh[1024 + d];
    const float* gi = Gi + ((size_t)srow * 32 + b) * 1536;
    float r = sigm_fast(gi[d] + ar);
    float z = sigm_fast(gi[512 + d] + az);
    float n = tanh_fast(gi[1024 + d] + r * an);
    float h2 = (1.f - z) * n + z * hcur[b * 512 + d];
    hnb[b * 512 + d] = f2bf(h2);
    hnf[b * 512 + d] = h2;
    ebo[((size_t)b * 64 + srow) * 1024 + (size_t)dir * 512 + d] = f2bf(h2);
    if (t == 63) hcat[(size_t)b * 1024 + (size_t)dir * 512 + d] = h2;
  }
}

// Decoder step part 1: gout[b][n] = s_t[b] . Wcat[n] (+decBhh for n>=512).
__global__ __launch_bounds__(512) void dec_proj(
    const unsigned short* __restrict__ Wcat, const float* __restrict__ decBhh,
    const unsigned short* __restrict__ sbf, float* __restrict__ gout, int t) {
  const int g = blockIdx.x, tid = threadIdx.x;
  __shared__ __align__(16) unsigned short slds[32 * 520];
  const unsigned short* sb = sbf + (t & 1) * 16384;
  for (int c = tid; c < 32 * 64; c += 512) {
    int r = c >> 6, seg = c & 63;
    *(short8*)(slds + r * 520 + seg * 8) = *(const short8*)(sb + r * 512 + seg * 8);
  }
  __syncthreads();
  const int w = tid >> 6, lane = tid & 63, fr = lane & 15, fq = lane >> 4;
  const int mt = w >> 2, nt = w & 3;
  int rc = g * 64 + nt * 16 + fr;
  const unsigned short* wrow = Wcat + (size_t)rc * 512;
  f32x4 acc = {0.f, 0.f, 0.f, 0.f};
#pragma unroll
  for (int k0 = 0; k0 < 512; k0 += 32) {
    short8 a = *(const short8*)(slds + (mt * 16 + fr) * 520 + k0 + fq * 8);
    short8 bq = *(const short8*)(wrow + k0 + fq * 8);
    acc = __builtin_amdgcn_mfma_f32_16x16x32_bf16(a, bq, acc, 0, 0, 0);
  }
  float bv = rc < 512 ? 0.f : decBhh[rc - 512];
#pragma unroll
  for (int j = 0; j < 4; ++j)
    gout[(size_t)(mt * 16 + fq * 4 + j) * 2048 + rc] = acc[j] + bv;
}

// Decoder step part 2: scores, softmax, context, gic, gates. One block per
// batch. Phase C vectorized (u32 paired bf16 loads, s-split + LDS combine).
__global__ __launch_bounds__(512) void dec_attn(
    const float* __restrict__ attnV,
    const unsigned short* __restrict__ epf,
    const u32* __restrict__ eb32,
    const u32* __restrict__ ep232,
    const float* __restrict__ Gie,
    const float* __restrict__ gout,
    unsigned short* __restrict__ sbf, float* __restrict__ sf32,
    unsigned short* __restrict__ Zbf, int t) {
  const int b = blockIdx.x, tid = threadIdx.x;
  __shared__ __align__(16) float gout_f[2048];
  __shared__ float raw[64], aaw[64];
  __shared__ float vlds[512];
  __shared__ __align__(8) float2 part[5][256];
  vlds[tid] = attnV[tid];
  *(float4*)(gout_f + tid * 4) = *(const float4*)(gout + (size_t)b * 2048 + tid * 4);
  __syncthreads();
  const int s_i = tid >> 3, l8 = tid & 7;
  {
    float part1 = 0.f;
    const float* gp = gout_f + l8 * 64;
    const unsigned short* ep = epf + ((size_t)b * 64 + s_i) * 512 + l8 * 64;
    const float* vv = vlds + l8 * 64;
#pragma unroll
    for (int jc = 0; jc < 8; ++jc) {
      short8 e8 = *(const short8*)(ep + jc * 8);
      float4 g0 = *(const float4*)(gp + jc * 8);
      float4 g1 = *(const float4*)(gp + jc * 8 + 4);
      float4 v0 = *(const float4*)(vv + jc * 8);
      float4 v1 = *(const float4*)(vv + jc * 8 + 4);
      part1 += tanh_fast(g0.x + bf2f((unsigned short)e8[0])) * v0.x;
      part1 += tanh_fast(g0.y + bf2f((unsigned short)e8[1])) * v0.y;
      part1 += tanh_fast(g0.z + bf2f((unsigned short)e8[2])) * v0.z;
      part1 += tanh_fast(g0.w + bf2f((unsigned short)e8[3])) * v0.w;
      part1 += tanh_fast(g1.x + bf2f((unsigned short)e8[4])) * v1.x;
      part1 += tanh_fast(g1.y + bf2f((unsigned short)e8[5])) * v1.y;
      part1 += tanh_fast(g1.z + bf2f((unsigned short)e8[6])) * v1.z;
      part1 += tanh_fast(g1.w + bf2f((unsigned short)e8[7])) * v1.w;
    }
    part1 += __shfl_xor(part1, 1);
    part1 += __shfl_xor(part1, 2);
    part1 += __shfl_xor(part1, 4);
    if (l8 == 0) raw[s_i] = part1;
  }
  __syncthreads();
  if (tid < 64) {
    float x = raw[tid];
    float m = x;
#pragma unroll
    for (int k = 1; k < 64; k <<= 1) m = fmaxf(m, __shfl_xor(m, k));
    float e = __expf(x - m);
    float s = e;
#pragma unroll
    for (int k = 1; k < 64; k <<= 1) s += __shfl_xor(s, k);
    aaw[tid] = e * __builtin_amdgcn_rcpf(s);
  }
  __syncthreads();
  {
    const int cp = tid & 255, sh = tid >> 8;
    const u32* eb = eb32 + (size_t)b * 32768 + cp;
    const u32* e2 = ep232 + (size_t)b * 49152 + cp;
    float p0x = 0.f, p0y = 0.f, p1x = 0.f, p1y = 0.f, p2x = 0.f, p2y = 0.f;
    float p3x = 0.f, p3y = 0.f, p4x = 0.f, p4y = 0.f;
    const int sbase = sh * 32;
#pragma unroll 4
    for (int i = 0; i < 32; ++i) {
      int s2 = sbase + i;
      float a = aaw[s2];
      u32 v0 = eb[(size_t)s2 * 512];
      u32 v1 = eb[(size_t)s2 * 512 + 256];
      u32 v2 = e2[(size_t)s2 * 768];
      u32 v3 = e2[(size_t)s2 * 768 + 256];
      u32 v4 = e2[(size_t)s2 * 768 + 512];
      p0x += a * bflo(v0); p0y += a * bfhi(v0);
      p1x += a * bflo(v1); p1y += a * bfhi(v1);
      p2x += a * bflo(v2); p2y += a * bfhi(v2);
      p3x += a * bflo(v3); p3y += a * bfhi(v3);
      p4x += a * bflo(v4); p4y += a * bfhi(v4);
    }
    if (sh == 0) {
      part[0][cp] = make_float2(p0x, p0y);
      part[1][cp] = make_float2(p1x, p1y);
      part[2][cp] = make_float2(p2x, p2y);
      part[3][cp] = make_float2(p3x, p3y);
      part[4][cp] = make_float2(p4x, p4y);
    }
    __syncthreads();
    if (sh == 1) {
      part[0][cp].x += p0x; part[0][cp].y += p0y;
      part[1][cp].x += p1x; part[1][cp].y += p1y;
      part[2][cp].x += p2x; part[2][cp].y += p2y;
      part[3][cp].x += p3x; part[3][cp].y += p3y;
      part[4][cp].x += p4x; part[4][cp].y += p4y;
    }
  }
  __syncthreads();
  size_t zrow = ((size_t)t * 32 + b) * 2048;
  {
    int slot = tid >> 8, cp2 = tid & 255;
    float2 cpair = part[slot][cp2];
    u32 pk = (u32)f2bf(cpair.x) | ((u32)f2bf(cpair.y) << 16);
    *(u32*)(Zbf + zrow + 512 + (size_t)(slot * 256 + cp2) * 2) = pk;
  }
  {
    int hp = tid >> 1, odd = tid & 1;
    float g0a = odd ? part[2][hp].y : part[2][hp].x;
    float g1a = odd ? part[3][hp].y : part[3][hp].x;
    float g2a = odd ? part[4][hp].y : part[4][hp].x;
    const float* gie = Gie + ((size_t)t * 32 + b) * 1536;
    float sprev = sf32[(t & 1) * 16384 + b * 512 + tid];
    float rr = sigm_fast(gie[tid] + g0a + gout_f[512 + tid]);
    float zz = sigm_fast(gie[512 + tid] + g1a + gout_f[1024 + tid]);
    float nn = tanh_fast(gie[1024 + tid] + g2a + rr * gout_f[1536 + tid]);
    float s2v = (1.f - zz) * nn + zz * sprev;
    sbf[((t + 1) & 1) * 16384 + b * 512 + tid] = f2bf(s2v);
    sf32[((t + 1) & 1) * 16384 + b * 512 + tid] = s2v;
    Zbf[zrow + tid] = f2bf(s2v);
  }
}

extern "C" void kernel_launch(void* const* d_in, const int* in_sizes, int n_in,
                              void* d_out, int out_size, void* d_ws, size_t ws_size,
                              hipStream_t stream) {
  (void)in_sizes; (void)n_in; (void)out_size;
  const int* src = (const int*)d_in[0];
  const int* trg = (const int*)d_in[1];
  const float* emb = (const float*)d_in[2];
  const float* encf_Wih = (const float*)d_in[3];
  const float* encf_Whh = (const float*)d_in[4];
  const float* encf_bih = (const float*)d_in[5];
  const float* encf_bhh = (const float*)d_in[6];
  const float* encb_Wih = (const float*)d_in[7];
  const float* encb_Whh = (const float*)d_in[8];
  const float* encb_bih = (const float*)d_in[9];
  const float* encb_bhh = (const float*)d_in[10];
  const float* fc_W = (const float*)d_in[11];
  const float* fc_b = (const float*)d_in[12];
  const float* attn_W = (const float*)d_in[13];
  const float* attn_v = (const float*)d_in[14];
  const float* dec_Wih = (const float*)d_in[15];
  const float* dec_Whh = (const float*)d_in[16];
  const float* dec_bih = (const float*)d_in[17];
  const float* dec_bhh = (const float*)d_in[18];
  const float* out_W = (const float*)d_in[19];
  const float* out_b = (const float*)d_in[20];
  float* out = (float*)d_out;

  char* p = (char*)d_ws;
  size_t off = 0;
  auto alloc = [&](size_t bytes) {
    void* r = p + off;
    off = (off + bytes + 255) & ~(size_t)255;
    return r;
  };
  unsigned short* xbf = (unsigned short*)alloc((size_t)2048 * 512 * 2);
  unsigned short* ebf = (unsigned short*)alloc((size_t)1536 * 512 * 2);
  unsigned short* Zbf = (unsigned short*)alloc((size_t)1536 * 2048 * 2);
  float* Gif = (float*)alloc((size_t)2048 * 1536 * 4);
  float* Gib = (float*)alloc((size_t)2048 * 1536 * 4);
  float* Gie = (float*)alloc((size_t)1536 * 1536 * 4);
  unsigned short* ebo = (unsigned short*)alloc((size_t)2048 * 1024 * 2);
  unsigned short* epf = (unsigned short*)alloc((size_t)2048 * 512 * 2);
  unsigned short* EP2b = (unsigned short*)alloc((size_t)2048 * 1536 * 2);
  unsigned short* whFbf = (unsigned short*)alloc((size_t)1536 * 512 * 2);
  unsigned short* whBbf = (unsigned short*)alloc((size_t)1536 * 512 * 2);
  unsigned short* Wcat = (unsigned short*)alloc((size_t)2048 * 512 * 2);
  unsigned short* hbf = (unsigned short*)alloc((size_t)2 * 2 * 32 * 512 * 2);
  float* hf32 = (float*)alloc((size_t)2 * 2 * 32 * 512 * 4);
  float* hcat = (float*)alloc((size_t)32 * 1024 * 4);
  unsigned short* sbf = (unsigned short*)alloc((size_t)2 * 32 * 512 * 2);
  float* sf32 = (float*)alloc((size_t)2 * 32 * 512 * 4);
  float* gout = (float*)alloc((size_t)32 * 2048 * 4);
  unsigned short* outWbf = (unsigned short*)alloc((size_t)32000 * 2048 * 2);
  const bool bigB = (off <= ws_size);

  prep_gather<<<8744, 128, 0, stream>>>(src, trg, emb, xbf, ebf, Zbf,
                                        out, hbf, hf32,
                                        encf_Whh, encb_Whh, attn_W, dec_Whh,
                                        whFbf, whBbf, Wcat);

  gemm_gi<<<dim3(16, 12, 3), 256, 0, stream>>>(
      xbf, ebf, encf_Wih, encb_Wih, dec_Wih, encf_bih, encb_bih, dec_bih,
      Gif, Gib, Gie);

  const int nCvt = bigB ? 200 : 0;
  for (int t = 0; t < 64; ++t)
    enc_step<<<32 + nCvt, 512, 0, stream>>>(Gif, Gib, whFbf, whBbf, encf_bhh, encb_bhh,
                                            hbf, hf32, ebo, hcat, out_W, outWbf, nCvt, t);

  gemm_fc<<<4, 256, 0, stream>>>(hcat, fc_W, fc_b, sf32, sbf);

  gemm_ep<<<dim3(16, 12, 2), 256, 0, stream>>>(ebo, attn_W, dec_Wih, epf, EP2b);

  for (int t = 0; t < 47; ++t) {
    dec_proj<<<32, 512, 0, stream>>>(Wcat, dec_bhh, sbf, gout, t);
    dec_attn<<<32, 512, 0, stream>>>(attn_v, epf, (const u32*)ebo, (const u32*)EP2b,
                                     Gie, gout, sbf, sf32, Zbf, t);
  }

  if (bigB) {
    hipFuncSetAttribute((const void*)gemm_big8,
                        hipFuncAttributeMaxDynamicSharedMemorySize, 131072);
    gemm_big8<<<750, 512, 131072, stream>>>(Zbf, outWbf, out_b, out);
  } else {
    gemm_kernel<true, false, false><<<dim3(12, 250), 256, 0, stream>>>(
        Zbf, 2048, out_W, 2048, 0, out_b, out, 32000, 2048, 1504, 32);
  }
}